// Round 4
// baseline (112.939 us; speedup 1.0000x reference)
//
#include <hip/hip_runtime.h>
#include <hip/hip_fp16.h>

// Problem: Topo_60653528154131
//   x:[256,3,256,25] f32, centres:[64,2] f32, sharpness:[64,2] f32 -> out:[64] f32
//
// Cost model (fitted R0-R3): dur_us = C + sum(kernel times), C ~= 65 us fixed
// (256MiB ws poison fill ~43us in the timed stream + ~20us launch/teardown;
// independent of kernel count). So: minimize TOTAL kernel time, and keep all
// heavy work distributed across blocks (R3's lesson: concentrating the fold +
// rounds on one CU cost +19us).
//
// 4-kernel pipeline:
//   K1 k_feat    : block n: mean_{c,t} x[n] -> feat row n (S1/S2 expansion) ->
//                  featG (stride 26) + per-row min/max. Also INF-inits Mp
//                  (256 blocks x 66 words = 128*132 exactly).
//   K2 k_dist    : block i: load featG -> LDS, D2 row i -> D16 (half bits),
//                  row-min key via DPP -> rowKeyG.
//   K3 k_contract: 256 blocks. Deterministic Boruvka round-1 replay from rowKeyG
//                  (identical cmap in every block), fold OWN row of D16 into
//                  Mp[ca][cb] via global atomicMin (distributed over 256 CUs).
//                  Block 0 records round-1 deaths + counts.
//   K4 k_mst     : ONE block. Load Mp (nc<=128) to LDS; single-wave parallel
//                  PRIM on the contracted graph (edge-weight multiset of any
//                  MST is identical -> same deaths multiset as Boruvka rounds;
//                  contracted-matrix-of-min-edges preserves the MST, same
//                  property round-0's rounds 2+ relied on). No block barriers,
//                  no per-round contraction. Then structure-element layer.
//
// ws layout:
//   featG [6656] f32 @ 0      (stride 26)
//   fmnG  [256]  f32 @ 26624
//   fmxG  [256]  f32 @ 27648
//   rowKeyG[256] u32 @ 28672
//   deathsG[256] f32 @ 29696
//   ncdcG [2]    u32 @ 30720
//   D16  [65536] u16 @ 65536
//   Mp   [128*132] u32 @ 196608

#define WS_FEAT 0
#define WS_FMN  26624
#define WS_FMX  27648
#define WS_RK   28672
#define WS_DTH  29696
#define WS_NCDC 30720
#define WS_D16  65536
#define WS_MP   196608

#define INF32 0xFFFFFFFFu
#define SA 132   // u32 stride of Mp

// ---------------- K1: mean + feat row + row min/max + Mp INF-init ----------------
__global__ void __launch_bounds__(256) k_feat(const float* __restrict__ x,
                                              float* __restrict__ featG,
                                              float* __restrict__ fmnG,
                                              float* __restrict__ fmxG,
                                              unsigned int* __restrict__ Mp) {
    __shared__ float sums[25];
    __shared__ float mrow[25];
    __shared__ float S12[2];
    __shared__ unsigned int bmn, bmx;
    const int n = blockIdx.x;
    const int tid = threadIdx.x;
    if (tid < 66) Mp[n * 66 + tid] = INF32;   // 256*66 = 16896 = 128*132 exactly
    if (tid < 25) sums[tid] = 0.0f;
    if (tid == 0) { bmn = 0x7F800000u; bmx = 0u; }
    __syncthreads();
    if (tid < 200) {
        const float* base = x + (long)n * 19200 + 4 * tid;
        float a0 = 0.f, a1 = 0.f, a2 = 0.f, a3 = 0.f;
        #pragma unroll
        for (int i = 0; i < 24; ++i) {
            float4 v = *reinterpret_cast<const float4*>(base + 800 * i);
            a0 += v.x; a1 += v.y; a2 += v.z; a3 += v.w;
        }
        const int v0 = (4 * tid) % 25;
        atomicAdd(&sums[v0], a0);
        atomicAdd(&sums[(v0 + 1) % 25], a1);
        atomicAdd(&sums[(v0 + 2) % 25], a2);
        atomicAdd(&sums[(v0 + 3) % 25], a3);
    }
    __syncthreads();
    if (tid < 25) mrow[tid] = sums[tid] * (1.0f / 768.0f);
    __syncthreads();
    if (tid == 0) {
        float S1 = 0.f, S2 = 0.f;
        #pragma unroll
        for (int v = 0; v < 25; ++v) { S1 += mrow[v]; S2 += mrow[v] * mrow[v]; }
        S12[0] = S1; S12[1] = S2;
    }
    __syncthreads();
    if (tid < 25) {
        const float r = mrow[tid];
        float q = S12[1] - 2.f * r * S12[0] + 25.f * r * r;
        q = fmaxf(q, 0.f);
        const float f = sqrtf(q);
        featG[n * 26 + tid] = f;
        atomicMin(&bmn, __float_as_uint(f));
        atomicMax(&bmx, __float_as_uint(f));
    }
    __syncthreads();
    if (tid == 0) { fmnG[n] = __uint_as_float(bmn); fmxG[n] = __uint_as_float(bmx); }
}

// wave64 min-reduce step via DPP: result in lane 63
template <int CTRL>
__device__ __forceinline__ unsigned int dpp_min_step(unsigned int v) {
    unsigned int t = (unsigned int)__builtin_amdgcn_update_dpp(
        (int)0xFFFFFFFF, (int)v, CTRL, 0xF, 0xF, false);
    return (t < v) ? t : v;
}

// ---------------- K2: D2 row + row-min key ----------------
__global__ void __launch_bounds__(256) k_dist(const float* __restrict__ featG,
                                              unsigned short* __restrict__ D16,
                                              unsigned int* __restrict__ rowKeyG) {
    __shared__ float featS[6656];          // stride 26 (2-way bank alias: free)
    __shared__ unsigned int wred[4];
    const int i = blockIdx.x;
    const int t = threadIdx.x;
    #pragma unroll
    for (int it = 0; it < 7; ++it) {
        const int o = it * 256 + t;
        if (o < 1664) reinterpret_cast<float4*>(featS)[o] =
            reinterpret_cast<const float4*>(featG)[o];
    }
    __syncthreads();
    float fi[25];
    #pragma unroll
    for (int v = 0; v < 25; ++v) fi[v] = featS[i * 26 + v];   // broadcast reads
    float s = 0.f;
    #pragma unroll
    for (int v = 0; v < 25; ++v) {
        const float d = fi[v] - featS[t * 26 + v];
        s += d * d;
    }
    const unsigned int w16 = (unsigned int)__half_as_ushort(__float2half(s));
    D16[i * 256 + t] = (unsigned short)w16;
    const unsigned int lo = (t < i) ? t : i, hi = (t < i) ? i : t;
    unsigned int key = (t == i) ? INF32 : ((w16 << 16) | (lo << 8) | hi);
    key = dpp_min_step<0x111>(key);
    key = dpp_min_step<0x112>(key);
    key = dpp_min_step<0x114>(key);
    key = dpp_min_step<0x118>(key);
    key = dpp_min_step<0x142>(key);
    key = dpp_min_step<0x143>(key);
    if ((t & 63) == 63) wred[t >> 6] = key;
    __syncthreads();
    if (t == 0) {
        const unsigned int b0 = wred[0] < wred[1] ? wred[0] : wred[1];
        const unsigned int b1 = wred[2] < wred[3] ? wred[2] : wred[3];
        rowKeyG[i] = b0 < b1 ? b0 : b1;
    }
}

// ---------------- wave0 Boruvka round-1 (verified R0 lineage) ----------------
template <bool RECORD>
__device__ __forceinline__ void wave0_phase(int n, int lane,
        unsigned int* rowKeyS, unsigned char* parentS, unsigned char* newidS,
        unsigned char* cmapS, float* deaths, unsigned int* ncS, unsigned int* dcS) {
    unsigned int par[4];
    #pragma unroll
    for (int s = 0; s < 4; ++s) {         // hook
        const int i = lane + 64 * s;
        if (i < n) {
            const unsigned int rk = rowKeyS[i];
            const unsigned int u = (rk >> 8) & 0xFFu, v = rk & 0xFFu;
            unsigned int p = (u == (unsigned int)i) ? v : u;
            if (rk == INF32) p = (unsigned int)i;
            par[s] = p;
            parentS[i] = (unsigned char)p;
        }
    }
    #pragma unroll
    for (int s = 0; s < 4; ++s) {         // break mutual 2-cycles
        const int i = lane + 64 * s;
        if (i < n) {
            const unsigned int p = par[s];
            if (p != (unsigned int)i) {
                if (parentS[p] == (unsigned char)i && (unsigned int)i < p) {
                    parentS[i] = (unsigned char)i;   // winner stays root
                } else if (RECORD) {
                    const unsigned int d = atomicAdd(dcS, 1u);
                    const unsigned int rk = rowKeyS[i];
                    deaths[d] = sqrtf(__half2float(__ushort_as_half(
                        (unsigned short)(rk >> 16))));
                }
            }
        }
    }
    for (;;) {                            // async pointer jump
        bool ch = false;
        #pragma unroll
        for (int s = 0; s < 4; ++s) {
            const int i = lane + 64 * s;
            if (i < n) {
                const unsigned char p0 = parentS[i];
                const unsigned char np = parentS[p0];
                if (np != p0) { ch = true; parentS[i] = np; }
            }
        }
        if (__ballot(ch) == 0ull) break;
    }
    bool isr[4];
    #pragma unroll
    for (int s = 0; s < 4; ++s) {
        const int i = lane + 64 * s;
        isr[s] = (i < n) && (parentS[i] == (unsigned char)i);
    }
    unsigned int base = 0;
    const unsigned long long below = (1ull << lane) - 1ull;
    #pragma unroll
    for (int s = 0; s < 4; ++s) {
        const unsigned long long mask = __ballot(isr[s]);   // uniform execution
        if (isr[s]) {
            const int i = lane + 64 * s;
            newidS[i] = (unsigned char)(base + __popcll(mask & below));
        }
        base += (unsigned int)__popcll(mask);
    }
    if (lane == 0) *ncS = base;
    #pragma unroll
    for (int s = 0; s < 4; ++s) {
        const int i = lane + 64 * s;
        if (i < n) cmapS[i] = newidS[parentS[i]];
    }
}

// ---------------- K3: distributed round-1 contraction (verified R0) ----------
__global__ void __launch_bounds__(256) k_contract(const unsigned short* __restrict__ D16g,
                                                  const unsigned int* __restrict__ rowKeyG,
                                                  unsigned int* __restrict__ Mp,
                                                  float* __restrict__ deathsG,
                                                  unsigned int* __restrict__ ncdcG) {
    __shared__ unsigned int rowKeyS[256];
    __shared__ unsigned char parentS[256], newidS[256], cmapS[256];
    __shared__ unsigned int ncS, dcS;
    __shared__ float deathsS[256];
    const int tid = threadIdx.x;
    const int b = blockIdx.x;
    rowKeyS[tid] = rowKeyG[tid];
    if (tid == 0) dcS = 0;
    __syncthreads();
    if (tid < 64) {
        if (b == 0)
            wave0_phase<true>(256, tid, rowKeyS, parentS, newidS, cmapS,
                              deathsS, &ncS, &dcS);
        else
            wave0_phase<false>(256, tid, rowKeyS, parentS, newidS, cmapS,
                               nullptr, &ncS, nullptr);
    }
    __syncthreads();
    if (b == 0) {   // publish round-1 deaths + counts (deterministic multiset)
        if (tid < dcS) deathsG[tid] = deathsS[tid];
        if (tid == 0) { ncdcG[0] = ncS; ncdcG[1] = dcS; }
    }
    // fold row b into Mp via global atomicMin (distributed across 256 CUs)
    const unsigned int ca = cmapS[b];
    const unsigned int cb = cmapS[tid];
    if (ca != cb) {
        const unsigned int w16 = (unsigned int)D16g[b * 256 + tid];
        const unsigned int lo = ca < cb ? ca : cb;
        const unsigned int hi = ca < cb ? cb : ca;
        atomicMin(&Mp[ca * SA + cb], (w16 << 16) | (lo << 8) | hi);
    }
}

// ---------------- K4: single-wave Prim on contracted graph + structure ----------
__global__ void __launch_bounds__(1024) k_mst(const unsigned int* __restrict__ Mp,
                                              const float* __restrict__ deathsG,
                                              const unsigned int* __restrict__ ncdcG,
                                              const float* __restrict__ fmnG,
                                              const float* __restrict__ fmxG,
                                              const float* __restrict__ centres,
                                              const float* __restrict__ sharp,
                                              float* __restrict__ out) {
    __shared__ unsigned int Mb[128 * SA];     // 67.6 KB contracted matrix
    __shared__ float deathsS[256];
    __shared__ unsigned int mmS[2];
    __shared__ float outpart[1024];
    __shared__ unsigned int ncS, dcS;
    const int tid = threadIdx.x;
    const int wv = tid >> 6, lane = tid & 63;

    if (tid == 0) {
        ncS = ncdcG[0]; dcS = ncdcG[1];
        mmS[0] = 0x7F800000u; mmS[1] = 0u;
    }
    if (tid < 256) deathsS[tid] = deathsG[tid];   // only [0,dc) meaningful
    __syncthreads();
    const int nc = (int)ncS;
    for (int idx = tid; idx < nc * SA; idx += 1024) Mb[idx] = Mp[idx];
    if (wv == 15) {                               // feat min/max reduce
        #pragma unroll
        for (int q = 0; q < 4; ++q) {
            const int j = lane * 4 + q;
            atomicMin(&mmS[0], __float_as_uint(fmnG[j]));
            atomicMax(&mmS[1], __float_as_uint(fmxG[j]));
        }
    }
    __syncthreads();

    if (wv == 0) {
        // ---- parallel Prim, 2 nodes/lane (nc <= 128), keyed u32 compare ----
        // key = (d16 << 16) | node_index (index < 128 -> low byte). Fake nodes
        // [nc,128) have Mp entries INF32 -> key 0xFFFF00xx, never selected while
        // a real node remains (real d16 <= 0x7BFF).
        const int dc = (int)dcS;
        unsigned int d0 = (Mb[lane]      & 0xFFFF0000u) | (unsigned)lane;
        unsigned int d1 = (Mb[64 + lane] & 0xFFFF0000u) | (unsigned)(64 + lane);
        unsigned int tb = 0;                      // in-tree bits for my 2 slots
        if (lane == 0) { tb = 1u; d0 = INF32; }   // node 0 starts in tree
        for (int it = 0; it < nc - 1; ++it) {
            unsigned int key = d0 < d1 ? d0 : d1;
            key = dpp_min_step<0x111>(key);
            key = dpp_min_step<0x112>(key);
            key = dpp_min_step<0x114>(key);
            key = dpp_min_step<0x118>(key);
            key = dpp_min_step<0x142>(key);
            key = dpp_min_step<0x143>(key);
            const unsigned int best =
                (unsigned int)__builtin_amdgcn_readlane((int)key, 63);
            const unsigned int j = best & 0xFFu;
            if (lane == 0)
                deathsS[dc + it] = sqrtf(__half2float(__ushort_as_half(
                    (unsigned short)(best >> 16))));
            const unsigned int lj = j & 63u, slot = j >> 6;
            if ((unsigned)lane == lj) {           // mark j in-tree
                tb |= (1u << slot);
                if (slot == 0u) d0 = INF32; else d1 = INF32;
            }
            const unsigned int rb = j * SA;
            const unsigned int n0 = (Mb[rb + lane]      & 0xFFFF0000u) | (unsigned)lane;
            const unsigned int n1 = (Mb[rb + 64 + lane] & 0xFFFF0000u) | (unsigned)(64 + lane);
            d0 = (tb & 1u) ? INF32 : (n0 < d0 ? n0 : d0);
            d1 = (tb & 2u) ? INF32 : (n1 < d1 ? n1 : d1);
        }
    }
    __syncthreads();

    // ---------------- structure-element layer (verified 16-partial form) -----
    const float mn = __uint_as_float(mmS[0]);
    const float mx = __uint_as_float(mmS[1]);
    const float inv = 1.0f / (mx - mn);
    const int k = tid & 63;
    const int part = tid >> 6;
    const float c0 = centres[2 * k], c1 = centres[2 * k + 1];
    const float s0 = sharp[2 * k],   s1 = sharp[2 * k + 1];
    const float t0 = c0 * c0 * s0 * s0;
    const float s1sq = s1 * s1;
    float acc = 0.f;
    for (int idx = part; idx < 255; idx += 16) {
        const float d = deathsS[idx] * inv - c1;
        acc += __expf(-(t0 + d * d * s1sq));
    }
    outpart[tid] = acc;
    __syncthreads();
    if (tid < 64) {
        float s = 0.f;
        #pragma unroll
        for (int pp = 0; pp < 16; ++pp) s += outpart[tid + 64 * pp];
        out[tid] = s;
    }
}

extern "C" void kernel_launch(void* const* d_in, const int* in_sizes, int n_in,
                              void* d_out, int out_size, void* d_ws, size_t ws_size,
                              hipStream_t stream) {
    const float* x       = (const float*)d_in[0];
    const float* centres = (const float*)d_in[1];
    const float* sharp   = (const float*)d_in[2];
    float* out = (float*)d_out;
    char* ws = (char*)d_ws;
    float*          featG = (float*)(ws + WS_FEAT);
    float*          fmnG  = (float*)(ws + WS_FMN);
    float*          fmxG  = (float*)(ws + WS_FMX);
    unsigned int*   rk    = (unsigned int*)(ws + WS_RK);
    float*          dth   = (float*)(ws + WS_DTH);
    unsigned int*   ncdc  = (unsigned int*)(ws + WS_NCDC);
    unsigned short* D16   = (unsigned short*)(ws + WS_D16);
    unsigned int*   Mp    = (unsigned int*)(ws + WS_MP);

    k_feat<<<256, 256, 0, stream>>>(x, featG, fmnG, fmxG, Mp);
    k_dist<<<256, 256, 0, stream>>>(featG, D16, rk);
    k_contract<<<256, 256, 0, stream>>>(D16, rk, Mp, dth, ncdc);
    k_mst<<<1, 1024, 0, stream>>>(Mp, dth, ncdc, fmnG, fmxG, centres, sharp, out);
}

// Round 5
// 106.452 us; speedup vs baseline: 1.0609x; 1.0609x over previous
//
#include <hip/hip_runtime.h>
#include <hip/hip_fp16.h>

// Problem: Topo_60653528154131
//   x:[256,3,256,25] f32, centres:[64,2] f32, sharpness:[64,2] f32 -> out:[64] f32
//
// Cost model (fitted R0-R4): dur_us = C + sum(kernel times), C ~= 65 us fixed
// (256MiB ws poison fill ~43us + launch/teardown). Small kernels run at IDLE
// CORE CLOCK (~500-600MHz; R3/R4 evidence: 1-wave Prim ~= 250cy/iter measured
// ~400-500ns/iter). So: minimize SERIAL CYCLES; distribute everything else.
// Single-wave Prim (R4) and 1-CU fold (R3) were both ~25us regressions vs
// R0's 16-wave Boruvka rounds. This round: verified-best composition:
//   K1 k_feat    (R4-verified): mean -> feat row n + per-row min/max + Mp init.
//   K2 k_dist    (R3/R4-verified): light D2 row + DPP row-min key (no feat
//                recompute -> ~5us cheaper than R0's k_dist).
//   K3 k_contract(R0-verified): distributed Boruvka round-1 fold into Mp.
//   K4 k_mst     (R0-verified): 16-wave Boruvka rounds 2+ on LDS ping-pong,
//                minmax from fmnG/fmxG (R4-verified reduce), structure layer.
//
// ws layout:
//   featG [6656] f32 @ 0      (stride 26)
//   fmnG  [256]  f32 @ 26624
//   fmxG  [256]  f32 @ 27648
//   rowKeyG[256] u32 @ 28672
//   deathsG[256] f32 @ 29696
//   ncdcG [2]    u32 @ 30720
//   D16  [65536] u16 @ 65536
//   Mp   [128*132] u32 @ 196608

#define WS_FEAT 0
#define WS_FMN  26624
#define WS_FMX  27648
#define WS_RK   28672
#define WS_DTH  29696
#define WS_NCDC 30720
#define WS_D16  65536
#define WS_MP   196608

#define INF32 0xFFFFFFFFu
#define SA 132   // u32 stride, buffer A (cap 128 rows)
#define SB 68    // u32 stride, buffer B (cap 64 rows)
#define OFF_B (128 * SA)

// ---------------- K1: mean + feat row + row min/max + Mp INF-init ----------------
__global__ void __launch_bounds__(256) k_feat(const float* __restrict__ x,
                                              float* __restrict__ featG,
                                              float* __restrict__ fmnG,
                                              float* __restrict__ fmxG,
                                              unsigned int* __restrict__ Mp) {
    __shared__ float sums[25];
    __shared__ float mrow[25];
    __shared__ float S12[2];
    __shared__ unsigned int bmn, bmx;
    const int n = blockIdx.x;
    const int tid = threadIdx.x;
    if (tid < 66) Mp[n * 66 + tid] = INF32;   // 256*66 = 16896 = 128*132 exactly
    if (tid < 25) sums[tid] = 0.0f;
    if (tid == 0) { bmn = 0x7F800000u; bmx = 0u; }
    __syncthreads();
    if (tid < 200) {
        const float* base = x + (long)n * 19200 + 4 * tid;
        float a0 = 0.f, a1 = 0.f, a2 = 0.f, a3 = 0.f;
        #pragma unroll
        for (int i = 0; i < 24; ++i) {
            float4 v = *reinterpret_cast<const float4*>(base + 800 * i);
            a0 += v.x; a1 += v.y; a2 += v.z; a3 += v.w;
        }
        const int v0 = (4 * tid) % 25;
        atomicAdd(&sums[v0], a0);
        atomicAdd(&sums[(v0 + 1) % 25], a1);
        atomicAdd(&sums[(v0 + 2) % 25], a2);
        atomicAdd(&sums[(v0 + 3) % 25], a3);
    }
    __syncthreads();
    if (tid < 25) mrow[tid] = sums[tid] * (1.0f / 768.0f);
    __syncthreads();
    if (tid == 0) {
        float S1 = 0.f, S2 = 0.f;
        #pragma unroll
        for (int v = 0; v < 25; ++v) { S1 += mrow[v]; S2 += mrow[v] * mrow[v]; }
        S12[0] = S1; S12[1] = S2;
    }
    __syncthreads();
    if (tid < 25) {
        const float r = mrow[tid];
        float q = S12[1] - 2.f * r * S12[0] + 25.f * r * r;
        q = fmaxf(q, 0.f);
        const float f = sqrtf(q);
        featG[n * 26 + tid] = f;
        atomicMin(&bmn, __float_as_uint(f));
        atomicMax(&bmx, __float_as_uint(f));
    }
    __syncthreads();
    if (tid == 0) { fmnG[n] = __uint_as_float(bmn); fmxG[n] = __uint_as_float(bmx); }
}

// wave64 min-reduce step via DPP: result in lane 63
template <int CTRL>
__device__ __forceinline__ unsigned int dpp_min_step(unsigned int v) {
    unsigned int t = (unsigned int)__builtin_amdgcn_update_dpp(
        (int)0xFFFFFFFF, (int)v, CTRL, 0xF, 0xF, false);
    return (t < v) ? t : v;
}

// ---------------- K2: D2 row + row-min key (light, R3/R4-verified) ----------------
__global__ void __launch_bounds__(256) k_dist(const float* __restrict__ featG,
                                              unsigned short* __restrict__ D16,
                                              unsigned int* __restrict__ rowKeyG) {
    __shared__ float featS[6656];          // stride 26
    __shared__ unsigned int wred[4];
    const int i = blockIdx.x;
    const int t = threadIdx.x;
    #pragma unroll
    for (int it = 0; it < 7; ++it) {
        const int o = it * 256 + t;
        if (o < 1664) reinterpret_cast<float4*>(featS)[o] =
            reinterpret_cast<const float4*>(featG)[o];
    }
    __syncthreads();
    float fi[25];
    #pragma unroll
    for (int v = 0; v < 25; ++v) fi[v] = featS[i * 26 + v];   // broadcast reads
    float s = 0.f;
    #pragma unroll
    for (int v = 0; v < 25; ++v) {
        const float d = fi[v] - featS[t * 26 + v];
        s += d * d;
    }
    const unsigned int w16 = (unsigned int)__half_as_ushort(__float2half(s));
    D16[i * 256 + t] = (unsigned short)w16;
    const unsigned int lo = (t < i) ? t : i, hi = (t < i) ? i : t;
    unsigned int key = (t == i) ? INF32 : ((w16 << 16) | (lo << 8) | hi);
    key = dpp_min_step<0x111>(key);
    key = dpp_min_step<0x112>(key);
    key = dpp_min_step<0x114>(key);
    key = dpp_min_step<0x118>(key);
    key = dpp_min_step<0x142>(key);
    key = dpp_min_step<0x143>(key);
    if ((t & 63) == 63) wred[t >> 6] = key;
    __syncthreads();
    if (t == 0) {
        const unsigned int b0 = wred[0] < wred[1] ? wred[0] : wred[1];
        const unsigned int b1 = wred[2] < wred[3] ? wred[2] : wred[3];
        rowKeyG[i] = b0 < b1 ? b0 : b1;
    }
}

// ---------------- wave0 Boruvka phase (R0-verified) ----------------
template <bool RECORD>
__device__ __forceinline__ void wave0_phase(int n, int lane,
        unsigned int* rowKeyS, unsigned char* parentS, unsigned char* newidS,
        unsigned char* cmapS, float* deaths, unsigned int* ncS, unsigned int* dcS) {
    unsigned int par[4];
    #pragma unroll
    for (int s = 0; s < 4; ++s) {         // hook
        const int i = lane + 64 * s;
        if (i < n) {
            const unsigned int rk = rowKeyS[i];
            const unsigned int u = (rk >> 8) & 0xFFu, v = rk & 0xFFu;
            unsigned int p = (u == (unsigned int)i) ? v : u;
            if (rk == INF32) p = (unsigned int)i;
            par[s] = p;
            parentS[i] = (unsigned char)p;
        }
    }
    #pragma unroll
    for (int s = 0; s < 4; ++s) {         // break mutual 2-cycles
        const int i = lane + 64 * s;
        if (i < n) {
            const unsigned int p = par[s];
            if (p != (unsigned int)i) {
                if (parentS[p] == (unsigned char)i && (unsigned int)i < p) {
                    parentS[i] = (unsigned char)i;   // winner stays root
                } else if (RECORD) {
                    const unsigned int d = atomicAdd(dcS, 1u);
                    const unsigned int rk = rowKeyS[i];
                    deaths[d] = sqrtf(__half2float(__ushort_as_half(
                        (unsigned short)(rk >> 16))));
                }
            }
        }
    }
    for (;;) {                            // async pointer jump
        bool ch = false;
        #pragma unroll
        for (int s = 0; s < 4; ++s) {
            const int i = lane + 64 * s;
            if (i < n) {
                const unsigned char p0 = parentS[i];
                const unsigned char np = parentS[p0];
                if (np != p0) { ch = true; parentS[i] = np; }
            }
        }
        if (__ballot(ch) == 0ull) break;
    }
    bool isr[4];
    #pragma unroll
    for (int s = 0; s < 4; ++s) {
        const int i = lane + 64 * s;
        isr[s] = (i < n) && (parentS[i] == (unsigned char)i);
    }
    unsigned int base = 0;
    const unsigned long long below = (1ull << lane) - 1ull;
    #pragma unroll
    for (int s = 0; s < 4; ++s) {
        const unsigned long long mask = __ballot(isr[s]);   // uniform execution
        if (isr[s]) {
            const int i = lane + 64 * s;
            newidS[i] = (unsigned char)(base + __popcll(mask & below));
        }
        base += (unsigned int)__popcll(mask);
    }
    if (lane == 0) *ncS = base;
    #pragma unroll
    for (int s = 0; s < 4; ++s) {
        const int i = lane + 64 * s;
        if (i < n) cmapS[i] = newidS[parentS[i]];
    }
}

// ---------------- K3: distributed round-1 contraction (R0-verified) ----------
__global__ void __launch_bounds__(256) k_contract(const unsigned short* __restrict__ D16g,
                                                  const unsigned int* __restrict__ rowKeyG,
                                                  unsigned int* __restrict__ Mp,
                                                  float* __restrict__ deathsG,
                                                  unsigned int* __restrict__ ncdcG) {
    __shared__ unsigned int rowKeyS[256];
    __shared__ unsigned char parentS[256], newidS[256], cmapS[256];
    __shared__ unsigned int ncS, dcS;
    __shared__ float deathsS[256];
    const int tid = threadIdx.x;
    const int b = blockIdx.x;
    rowKeyS[tid] = rowKeyG[tid];
    if (tid == 0) dcS = 0;
    __syncthreads();
    if (tid < 64) {
        if (b == 0)
            wave0_phase<true>(256, tid, rowKeyS, parentS, newidS, cmapS,
                              deathsS, &ncS, &dcS);
        else
            wave0_phase<false>(256, tid, rowKeyS, parentS, newidS, cmapS,
                               nullptr, &ncS, nullptr);
    }
    __syncthreads();
    if (b == 0) {   // publish round-1 deaths + counts (deterministic multiset)
        if (tid < dcS) deathsG[tid] = deathsS[tid];
        if (tid == 0) { ncdcG[0] = ncS; ncdcG[1] = dcS; }
    }
    // fold row b into Mp via global atomicMin (distributed across 256 CUs)
    const unsigned int ca = cmapS[b];
    const unsigned int cb = cmapS[tid];
    if (ca != cb) {
        const unsigned int w16 = (unsigned int)D16g[b * 256 + tid];
        const unsigned int lo = ca < cb ? ca : cb;
        const unsigned int hi = ca < cb ? cb : ca;
        atomicMin(&Mp[ca * SA + cb], (w16 << 16) | (lo << 8) | hi);
    }
}

// ---------------- K4: 16-wave Boruvka rounds 2+ (R0-verified) + structure ------
__global__ void __launch_bounds__(1024) k_mst(const unsigned int* __restrict__ Mp,
                                              const float* __restrict__ deathsG,
                                              const unsigned int* __restrict__ ncdcG,
                                              const float* __restrict__ fmnG,
                                              const float* __restrict__ fmxG,
                                              const float* __restrict__ centres,
                                              const float* __restrict__ sharp,
                                              float* __restrict__ out) {
    __shared__ unsigned int Mb[128 * SA + 64 * SB];   // 84.5 KB ping-pong
    __shared__ unsigned int rowKeyS[256];
    __shared__ unsigned char parentS[256], newidS[256], cmapS[256];
    __shared__ unsigned int ncS, dcS;
    __shared__ float deaths[256];
    __shared__ unsigned int mmS[2];
    __shared__ float outpart[1024];
    const int tid = threadIdx.x;
    const int wv = tid >> 6, lane = tid & 63;

    // round-1 results from k_contract: n, deaths so far; minmax from per-row
    if (tid == 0) {
        ncS = ncdcG[0]; dcS = ncdcG[1];
        mmS[0] = 0x7F800000u; mmS[1] = 0u;
    }
    if (tid < 256) deaths[tid] = deathsG[tid];   // only [0,dcS) meaningful
    __syncthreads();
    int n = (int)ncS;

    // load contracted matrix Mp (n x n, stride SA) into buffer A; wave15 also
    // reduces the 256 per-row min/max values (R4-verified pattern)
    for (int idx = tid; idx < n * SA; idx += 1024) Mb[idx] = Mp[idx];
    if (wv == 15) {
        #pragma unroll
        for (int q = 0; q < 4; ++q) {
            const int j = lane * 4 + q;
            atomicMin(&mmS[0], __float_as_uint(fmnG[j]));
            atomicMax(&mmS[1], __float_as_uint(fmxG[j]));
        }
    }
    __syncthreads();

    // rounds 2+ (R0-verified 16-wave structure; <=8 rounds, 12 = hang guard)
    int srcOff = 0, srcStr = SA, dstOff = OFF_B, dstStr = SB;
    for (int round = 0; round < 12 && n > 1; ++round) {
        if (tid < n) rowKeyS[tid] = INF32;
        __syncthreads();
        if (tid < 8 * n) {                 // scan: 8 threads per row
            const int a = tid >> 3, sub = tid & 7;
            const unsigned int* row = &Mb[srcOff + a * srcStr];
            unsigned int best = INF32;
            for (int b2 = sub; b2 < n; b2 += 8) {
                const unsigned int v = row[b2];
                best = v < best ? v : best;
            }
            if (best != INF32) atomicMin(&rowKeyS[a], best);
        }
        __syncthreads();
        if (tid < 64)
            wave0_phase<true>(n, tid, rowKeyS, parentS, newidS, cmapS,
                              deaths, &ncS, &dcS);
        __syncthreads();
        const int nc = (int)ncS;
        if (nc > 1) {                      // contract src -> dst
            for (int w = tid; w < nc * dstStr; w += 1024) Mb[dstOff + w] = INF32;
            __syncthreads();
            if (tid < 8 * n) {
                const int a = tid >> 3, sub = tid & 7;
                const unsigned int ca = cmapS[a];
                const unsigned int* row = &Mb[srcOff + a * srcStr];
                for (int b2 = sub; b2 < n; b2 += 8) {
                    const unsigned int cb = cmapS[b2];
                    const unsigned int v = row[b2];
                    if (ca != cb && v != INF32) {
                        const unsigned int lo = ca < cb ? ca : cb;
                        const unsigned int hi = ca < cb ? cb : ca;
                        atomicMin(&Mb[dstOff + ca * dstStr + cb],
                                  (v & 0xFFFF0000u) | (lo << 8) | hi);
                    }
                }
            }
            __syncthreads();
        }
        const int t1 = srcOff; srcOff = dstOff; dstOff = t1;
        const int t2 = srcStr; srcStr = dstStr; dstStr = t2;
        n = nc;
    }

    // structure-element layer (verified 16-partial form)
    const float mn = __uint_as_float(mmS[0]);
    const float mx = __uint_as_float(mmS[1]);
    const float inv = 1.0f / (mx - mn);
    const int k = tid & 63;
    const int part = tid >> 6;
    const float c0 = centres[2 * k], c1 = centres[2 * k + 1];
    const float s0 = sharp[2 * k],   s1 = sharp[2 * k + 1];
    const float t0 = c0 * c0 * s0 * s0;
    const float s1sq = s1 * s1;
    float acc = 0.f;
    for (int idx = part; idx < 255; idx += 16) {
        const float d = deaths[idx] * inv - c1;
        acc += __expf(-(t0 + d * d * s1sq));
    }
    outpart[tid] = acc;
    __syncthreads();
    if (tid < 64) {
        float s = 0.f;
        #pragma unroll
        for (int pp = 0; pp < 16; ++pp) s += outpart[tid + 64 * pp];
        out[tid] = s;
    }
}

extern "C" void kernel_launch(void* const* d_in, const int* in_sizes, int n_in,
                              void* d_out, int out_size, void* d_ws, size_t ws_size,
                              hipStream_t stream) {
    const float* x       = (const float*)d_in[0];
    const float* centres = (const float*)d_in[1];
    const float* sharp   = (const float*)d_in[2];
    float* out = (float*)d_out;
    char* ws = (char*)d_ws;
    float*          featG = (float*)(ws + WS_FEAT);
    float*          fmnG  = (float*)(ws + WS_FMN);
    float*          fmxG  = (float*)(ws + WS_FMX);
    unsigned int*   rk    = (unsigned int*)(ws + WS_RK);
    float*          dth   = (float*)(ws + WS_DTH);
    unsigned int*   ncdc  = (unsigned int*)(ws + WS_NCDC);
    unsigned short* D16   = (unsigned short*)(ws + WS_D16);
    unsigned int*   Mp    = (unsigned int*)(ws + WS_MP);

    k_feat<<<256, 256, 0, stream>>>(x, featG, fmnG, fmxG, Mp);
    k_dist<<<256, 256, 0, stream>>>(featG, D16, rk);
    k_contract<<<256, 256, 0, stream>>>(D16, rk, Mp, dth, ncdc);
    k_mst<<<1, 1024, 0, stream>>>(Mp, dth, ncdc, fmnG, fmxG, centres, sharp, out);
}

// Round 7
// 91.554 us; speedup vs baseline: 1.2336x; 1.1627x over previous
//
#include <hip/hip_runtime.h>
#include <hip/hip_fp16.h>

// Problem: Topo_60653528154131
//   x:[256,3,256,25] f32, centres:[64,2] f32, sharpness:[64,2] f32 -> out:[64] f32
//
// Cost model (fitted R0-R5): dur_us = C + sum(kernel times); C ~= 60-70 us fixed
// (256MiB harness ws poison fill ~43us in-stream + launch/teardown), with a
// +-10us cross-session offset. Kernels run at un-ramped clock -> serial cycles
// and BARRIERS dominate tiny kernels. Same verified 4-kernel algorithm,
// minus barriers:
//   K1 k_feat    : mean -> feat row n (parallel S1/S2, 3 barriers) + Mp init.
//   K2 k_dist    : light D2 row + DPP row-min key + inline feat minmax (blk 0 -> mm).
//   K3 k_contract: distributed Boruvka round-1 fold into Mp (R0-verified).
//   K4 k_mst     : 16-wave Boruvka rounds 2+, 3 barriers/round (dst-init fused
//                  into scan, rowKey-init fused into fold), uint4 Mp load,
//                  early-exit; structure layer.
//
// (Round-6 bench was an infra failure — container acquisition; kernel audited,
// no hang/fault path found; resubmitting unchanged for a clean measurement.)
//
// ws layout:
//   featG [6656] f32 @ 0      (stride 26)
//   mm    [2]    u32 @ 26624
//   rowKeyG[256] u32 @ 28672
//   deathsG[256] f32 @ 29696
//   ncdcG [2]    u32 @ 30720
//   D16  [65536] u16 @ 65536
//   Mp   [128*132] u32 @ 196608

#define WS_FEAT 0
#define WS_MM   26624
#define WS_RK   28672
#define WS_DTH  29696
#define WS_NCDC 30720
#define WS_D16  65536
#define WS_MP   196608

#define INF32 0xFFFFFFFFu
#define SA 132   // u32 stride, buffer A (cap 128 rows)
#define SB 68    // u32 stride, buffer B (cap 64 rows)
#define OFF_B (128 * SA)

// ---------------- K1: mean + feat row + Mp INF-init ----------------
__global__ void __launch_bounds__(256) k_feat(const float* __restrict__ x,
                                              float* __restrict__ featG,
                                              unsigned int* __restrict__ Mp) {
    __shared__ float sums[25];
    __shared__ float mrow[25];
    const int n = blockIdx.x;
    const int tid = threadIdx.x;
    if (tid < 66) Mp[n * 66 + tid] = INF32;   // 256*66 = 16896 = 128*132 exactly
    if (tid < 25) sums[tid] = 0.0f;
    __syncthreads();
    if (tid < 200) {
        const float* base = x + (long)n * 19200 + 4 * tid;
        float a0 = 0.f, a1 = 0.f, a2 = 0.f, a3 = 0.f;
        #pragma unroll
        for (int i = 0; i < 24; ++i) {
            float4 v = *reinterpret_cast<const float4*>(base + 800 * i);
            a0 += v.x; a1 += v.y; a2 += v.z; a3 += v.w;
        }
        const int v0 = (4 * tid) % 25;
        atomicAdd(&sums[v0], a0);
        atomicAdd(&sums[(v0 + 1) % 25], a1);
        atomicAdd(&sums[(v0 + 2) % 25], a2);
        atomicAdd(&sums[(v0 + 3) % 25], a3);
    }
    __syncthreads();
    if (tid < 25) mrow[tid] = sums[tid] * (1.0f / 768.0f);
    __syncthreads();
    if (tid < 25) {
        // parallel redundant S1/S2 (same FP order as the serial version ->
        // bit-identical), saves a barrier + serial tid==0 section
        float S1 = 0.f, S2 = 0.f;
        #pragma unroll
        for (int v = 0; v < 25; ++v) {
            const float mv = mrow[v];
            S1 += mv; S2 += mv * mv;
        }
        const float r = mrow[tid];
        float q = S2 - 2.f * r * S1 + 25.f * r * r;
        q = fmaxf(q, 0.f);
        featG[n * 26 + tid] = sqrtf(q);
    }
}

// wave64 min-reduce step via DPP: result in lane 63
template <int CTRL>
__device__ __forceinline__ unsigned int dpp_min_step(unsigned int v) {
    unsigned int t = (unsigned int)__builtin_amdgcn_update_dpp(
        (int)0xFFFFFFFF, (int)v, CTRL, 0xF, 0xF, false);
    return (t < v) ? t : v;
}

// ---------------- K2: D2 row + row-min key + minmax (blk0 -> mm) ----------------
__global__ void __launch_bounds__(256) k_dist(const float* __restrict__ featG,
                                              unsigned short* __restrict__ D16,
                                              unsigned int* __restrict__ rowKeyG,
                                              unsigned int* __restrict__ mm) {
    __shared__ float featS[6656];          // stride 26
    __shared__ unsigned int wred[4];
    __shared__ unsigned int bmn, bmx;
    const int i = blockIdx.x;
    const int t = threadIdx.x;
    if (t == 0) { bmn = 0x7F800000u; bmx = 0u; }
    #pragma unroll
    for (int it = 0; it < 7; ++it) {
        const int o = it * 256 + t;
        if (o < 1664) reinterpret_cast<float4*>(featS)[o] =
            reinterpret_cast<const float4*>(featG)[o];
    }
    __syncthreads();
    float fi[25];
    #pragma unroll
    for (int v = 0; v < 25; ++v) fi[v] = featS[i * 26 + v];   // broadcast reads
    float s = 0.f, fmn = 1e30f, fmx = -1e30f;
    #pragma unroll
    for (int v = 0; v < 25; ++v) {
        const float ft = featS[t * 26 + v];        // row t (thread-owned)
        const float d = fi[v] - ft;
        s += d * d;
        fmn = fminf(fmn, ft); fmx = fmaxf(fmx, ft);
    }
    if (i == 0) {   // feat >= 0 -> uint compare == float compare
        atomicMin(&bmn, __float_as_uint(fmn));
        atomicMax(&bmx, __float_as_uint(fmx));
    }
    const unsigned int w16 = (unsigned int)__half_as_ushort(__float2half(s));
    D16[i * 256 + t] = (unsigned short)w16;
    const unsigned int lo = (t < i) ? t : i, hi = (t < i) ? i : t;
    unsigned int key = (t == i) ? INF32 : ((w16 << 16) | (lo << 8) | hi);
    key = dpp_min_step<0x111>(key);
    key = dpp_min_step<0x112>(key);
    key = dpp_min_step<0x114>(key);
    key = dpp_min_step<0x118>(key);
    key = dpp_min_step<0x142>(key);
    key = dpp_min_step<0x143>(key);
    if ((t & 63) == 63) wred[t >> 6] = key;
    __syncthreads();
    if (t == 0) {
        const unsigned int b0 = wred[0] < wred[1] ? wred[0] : wred[1];
        const unsigned int b1 = wred[2] < wred[3] ? wred[2] : wred[3];
        rowKeyG[i] = b0 < b1 ? b0 : b1;
        if (i == 0) { mm[0] = bmn; mm[1] = bmx; }
    }
}

// ---------------- wave0 Boruvka phase (R0-verified) ----------------
template <bool RECORD>
__device__ __forceinline__ void wave0_phase(int n, int lane,
        unsigned int* rowKeyS, unsigned char* parentS, unsigned char* newidS,
        unsigned char* cmapS, float* deaths, unsigned int* ncS, unsigned int* dcS) {
    unsigned int par[4];
    #pragma unroll
    for (int s = 0; s < 4; ++s) {         // hook
        const int i = lane + 64 * s;
        if (i < n) {
            const unsigned int rk = rowKeyS[i];
            const unsigned int u = (rk >> 8) & 0xFFu, v = rk & 0xFFu;
            unsigned int p = (u == (unsigned int)i) ? v : u;
            if (rk == INF32) p = (unsigned int)i;
            par[s] = p;
            parentS[i] = (unsigned char)p;
        }
    }
    #pragma unroll
    for (int s = 0; s < 4; ++s) {         // break mutual 2-cycles
        const int i = lane + 64 * s;
        if (i < n) {
            const unsigned int p = par[s];
            if (p != (unsigned int)i) {
                if (parentS[p] == (unsigned char)i && (unsigned int)i < p) {
                    parentS[i] = (unsigned char)i;   // winner stays root
                } else if (RECORD) {
                    const unsigned int d = atomicAdd(dcS, 1u);
                    const unsigned int rk = rowKeyS[i];
                    deaths[d] = sqrtf(__half2float(__ushort_as_half(
                        (unsigned short)(rk >> 16))));
                }
            }
        }
    }
    for (;;) {                            // async pointer jump
        bool ch = false;
        #pragma unroll
        for (int s = 0; s < 4; ++s) {
            const int i = lane + 64 * s;
            if (i < n) {
                const unsigned char p0 = parentS[i];
                const unsigned char np = parentS[p0];
                if (np != p0) { ch = true; parentS[i] = np; }
            }
        }
        if (__ballot(ch) == 0ull) break;
    }
    bool isr[4];
    #pragma unroll
    for (int s = 0; s < 4; ++s) {
        const int i = lane + 64 * s;
        isr[s] = (i < n) && (parentS[i] == (unsigned char)i);
    }
    unsigned int base = 0;
    const unsigned long long below = (1ull << lane) - 1ull;
    #pragma unroll
    for (int s = 0; s < 4; ++s) {
        const unsigned long long mask = __ballot(isr[s]);   // uniform execution
        if (isr[s]) {
            const int i = lane + 64 * s;
            newidS[i] = (unsigned char)(base + __popcll(mask & below));
        }
        base += (unsigned int)__popcll(mask);
    }
    if (lane == 0) *ncS = base;
    #pragma unroll
    for (int s = 0; s < 4; ++s) {
        const int i = lane + 64 * s;
        if (i < n) cmapS[i] = newidS[parentS[i]];
    }
}

// ---------------- K3: distributed round-1 contraction (R0-verified) ----------
__global__ void __launch_bounds__(256) k_contract(const unsigned short* __restrict__ D16g,
                                                  const unsigned int* __restrict__ rowKeyG,
                                                  unsigned int* __restrict__ Mp,
                                                  float* __restrict__ deathsG,
                                                  unsigned int* __restrict__ ncdcG) {
    __shared__ unsigned int rowKeyS[256];
    __shared__ unsigned char parentS[256], newidS[256], cmapS[256];
    __shared__ unsigned int ncS, dcS;
    __shared__ float deathsS[256];
    const int tid = threadIdx.x;
    const int b = blockIdx.x;
    rowKeyS[tid] = rowKeyG[tid];
    if (tid == 0) dcS = 0;
    __syncthreads();
    if (tid < 64) {
        if (b == 0)
            wave0_phase<true>(256, tid, rowKeyS, parentS, newidS, cmapS,
                              deathsS, &ncS, &dcS);
        else
            wave0_phase<false>(256, tid, rowKeyS, parentS, newidS, cmapS,
                               nullptr, &ncS, nullptr);
    }
    __syncthreads();
    if (b == 0) {   // publish round-1 deaths + counts (deterministic multiset)
        if (tid < dcS) deathsG[tid] = deathsS[tid];
        if (tid == 0) { ncdcG[0] = ncS; ncdcG[1] = dcS; }
    }
    // fold row b into Mp via global atomicMin (distributed across 256 CUs)
    const unsigned int ca = cmapS[b];
    const unsigned int cb = cmapS[tid];
    if (ca != cb) {
        const unsigned int w16 = (unsigned int)D16g[b * 256 + tid];
        const unsigned int lo = ca < cb ? ca : cb;
        const unsigned int hi = ca < cb ? cb : ca;
        atomicMin(&Mp[ca * SA + cb], (w16 << 16) | (lo << 8) | hi);
    }
}

// ---------------- K4: 16-wave Boruvka rounds 2+ (3 barriers/round) + structure --
__global__ void __launch_bounds__(1024) k_mst(const unsigned int* __restrict__ Mp,
                                              const float* __restrict__ deathsG,
                                              const unsigned int* __restrict__ ncdcG,
                                              const unsigned int* __restrict__ mm,
                                              const float* __restrict__ centres,
                                              const float* __restrict__ sharp,
                                              float* __restrict__ out) {
    __shared__ unsigned int Mb[128 * SA + 64 * SB];   // 84.5 KB ping-pong
    __shared__ unsigned int rowKeyS[128];             // rounds 2+: n <= 128
    __shared__ unsigned char parentS[128], newidS[128], cmapS[128];
    __shared__ unsigned int ncS, dcS;
    __shared__ float deaths[256];
    __shared__ float outpart[1024];
    const int tid = threadIdx.x;

    if (tid == 0) { ncS = ncdcG[0]; dcS = ncdcG[1]; }
    if (tid < 256) deaths[tid] = deathsG[tid];   // only [0,dcS) meaningful
    if (tid < 128) rowKeyS[tid] = INF32;         // pre-init for first round
    __syncthreads();
    int n = (int)ncS;

    // vectorized load of contracted matrix (SA=132 -> 33 uint4 per row)
    for (int idx = tid; idx < n * 33; idx += 1024)
        reinterpret_cast<uint4*>(Mb)[idx] =
            reinterpret_cast<const uint4*>(Mp)[idx];
    __syncthreads();

    // rounds 2+ : 3 barriers per round. Invariants:
    //  - rowKeyS[0..n) == INF32 at round entry (init'd by prev fold phase / prologue)
    //  - nc <= n/2 every round (complete graph -> no singleton components)
    int srcOff = 0, srcStr = SA, dstOff = OFF_B, dstStr = SB;
    for (int round = 0; round < 12 && n > 1; ++round) {
        // phase A: row-min scan (8 threads/row) + dst INF-init (disjoint regions)
        if (tid < 8 * n) {
            const int a = tid >> 3, sub = tid & 7;
            const unsigned int* row = &Mb[srcOff + a * srcStr];
            unsigned int best = INF32;
            for (int b2 = sub; b2 < n; b2 += 8) {
                const unsigned int v = row[b2];
                best = v < best ? v : best;
            }
            if (best != INF32) atomicMin(&rowKeyS[a], best);
        }
        const int dstCap = (n >> 1) * dstStr;
        for (int w = tid; w < dstCap; w += 1024) Mb[dstOff + w] = INF32;
        __syncthreads();
        // phase B: hook + renumber (wave 0)
        if (tid < 64)
            wave0_phase<true>(n, tid, rowKeyS, parentS, newidS, cmapS,
                              deaths, &ncS, &dcS);
        __syncthreads();
        const int nc = (int)ncS;
        if (nc <= 1) break;               // deaths complete
        // phase C: fold src -> dst + next-round rowKey INF-init
        if (tid < 8 * n) {
            const int a = tid >> 3, sub = tid & 7;
            const unsigned int ca = cmapS[a];
            const unsigned int* row = &Mb[srcOff + a * srcStr];
            for (int b2 = sub; b2 < n; b2 += 8) {
                const unsigned int cb = cmapS[b2];
                const unsigned int v = row[b2];
                if (ca != cb && v != INF32) {
                    const unsigned int lo = ca < cb ? ca : cb;
                    const unsigned int hi = ca < cb ? cb : ca;
                    atomicMin(&Mb[dstOff + ca * dstStr + cb],
                              (v & 0xFFFF0000u) | (lo << 8) | hi);
                }
            }
        }
        for (int j = tid; j < (n >> 1); j += 1024) rowKeyS[j] = INF32;
        __syncthreads();
        const int t1 = srcOff; srcOff = dstOff; dstOff = t1;
        const int t2 = srcStr; srcStr = dstStr; dstStr = t2;
        n = nc;
    }

    // structure-element layer (verified 16-partial form)
    const float mn = __uint_as_float(mm[0]);
    const float mx = __uint_as_float(mm[1]);
    const float inv = 1.0f / (mx - mn);
    const int k = tid & 63;
    const int part = tid >> 6;
    const float c0 = centres[2 * k], c1 = centres[2 * k + 1];
    const float s0 = sharp[2 * k],   s1 = sharp[2 * k + 1];
    const float t0 = c0 * c0 * s0 * s0;
    const float s1sq = s1 * s1;
    float acc = 0.f;
    for (int idx = part; idx < 255; idx += 16) {
        const float d = deaths[idx] * inv - c1;
        acc += __expf(-(t0 + d * d * s1sq));
    }
    outpart[tid] = acc;
    __syncthreads();
    if (tid < 64) {
        float s = 0.f;
        #pragma unroll
        for (int pp = 0; pp < 16; ++pp) s += outpart[tid + 64 * pp];
        out[tid] = s;
    }
}

extern "C" void kernel_launch(void* const* d_in, const int* in_sizes, int n_in,
                              void* d_out, int out_size, void* d_ws, size_t ws_size,
                              hipStream_t stream) {
    const float* x       = (const float*)d_in[0];
    const float* centres = (const float*)d_in[1];
    const float* sharp   = (const float*)d_in[2];
    float* out = (float*)d_out;
    char* ws = (char*)d_ws;
    float*          featG = (float*)(ws + WS_FEAT);
    unsigned int*   mm    = (unsigned int*)(ws + WS_MM);
    unsigned int*   rk    = (unsigned int*)(ws + WS_RK);
    float*          dth   = (float*)(ws + WS_DTH);
    unsigned int*   ncdc  = (unsigned int*)(ws + WS_NCDC);
    unsigned short* D16   = (unsigned short*)(ws + WS_D16);
    unsigned int*   Mp    = (unsigned int*)(ws + WS_MP);

    k_feat<<<256, 256, 0, stream>>>(x, featG, Mp);
    k_dist<<<256, 256, 0, stream>>>(featG, D16, rk, mm);
    k_contract<<<256, 256, 0, stream>>>(D16, rk, Mp, dth, ncdc);
    k_mst<<<1, 1024, 0, stream>>>(Mp, dth, ncdc, mm, centres, sharp, out);
}